// Round 16
// baseline (232.701 us; speedup 1.0000x reference)
//
#include <hip/hip_runtime.h>
#include <math.h>

// Neural Additive Model: 256 per-feature MLPs 1->128->64->32->1 (ReLU), summed.
// B=8192, fp32 in/out.
//
// Exact rank-table decomposition: pre-relu h2[b,k] = x_b*Sw[r,k] + Sb[r,k],
// r = #(sorted layer-1 thresholds < x_b). Layer 3 on f16 MFMA 32x32x16
// (A=W3^T, B=h2), layer 4 reduced in-register + 1 shfl, 1 atomic/elem.
//
// Round 16: R15 was latency-bound (occ 37%, VALU 30%, LDS ~40%): the fused
// 1024-thr/45.6KB block caps residency AND rebuilds the table twice/feature.
// Split:
//  * build_tables (grid 256): phase A once per feature, table -> ws (9.2 MB,
//    coalesced f4 copy-out). Out-init folded in.
//  * nam_main (grid 1024 = feature x quarter, 512 thr, 35.6 KB LDS): table
//    loaded from global (L3), then R15's phase B. 4 blocks/CU = 32 waves/CU.
//    launch_bounds(512,8) caps VGPR 64 >= R15's measured 48 -> no spill.

#define NF   256
#define NH1  128
#define NH2  64
#define NH3  32
#define NB   8192

#define NRANK 129
#define ROW4  17                      // uint4 per table row (16 data + 1 pad)
#define ROWH  136                     // halfwords per row
#define TBLDW 8960                    // dword stride per feature in ws (128 tkey + 8772 tbl, padded)

typedef float    f32x16 __attribute__((ext_vector_type(16)));
typedef unsigned u32x4  __attribute__((ext_vector_type(4)));
typedef _Float16 h16x2  __attribute__((ext_vector_type(2)));
typedef _Float16 h16x8  __attribute__((ext_vector_type(8)));

// h2 pair: relu(x*Sw + Sb) on 2 packed f16 channels -> one B-frag dword
__device__ __forceinline__ unsigned pkh2(unsigned sw, unsigned sb, h16x2 xh) {
    h16x2 r = __builtin_elementwise_fma(xh, __builtin_bit_cast(h16x2, sw),
                                            __builtin_bit_cast(h16x2, sb));
    h16x2 hz = {(_Float16)0.f, (_Float16)0.f};
    return __builtin_bit_cast(unsigned, __builtin_elementwise_max(r, hz));
}

// ---------------- build: one block (512 thr) per feature; table -> ws ----------------
__global__ __launch_bounds__(512) void build_tables(
    const float* __restrict__ W1, const float* __restrict__ b1,
    const float* __restrict__ W2, const float* __restrict__ b2,
    const float* __restrict__ bias, float* __restrict__ out,
    unsigned* __restrict__ ws)
{
    __shared__ u32x4 SP4[NRANK * ROW4];    // 35.1 KB packed f16 table
    __shared__ float tkey[NH1];
    __shared__ int   tidx[NH1];
    __shared__ float w1s[NH1], b1s[NH1];
    __shared__ float Pbw[8][NH2], Pbb[8][NH2], Pdw[8][NH2], Pdb[8][NH2]; // 8 KB

    const int f = blockIdx.x;
    const int t = (int)threadIdx.x;
    _Float16* SPh = (_Float16*)SP4;

    // fused out-init (out poisoned before every launch; atomics add onto bias)
    const int gid = f * 512 + t;
    if (gid < NB) out[gid] = bias[0];

    const float* __restrict__ gw2 = W2 + (size_t)f * NH1 * NH2;
    if (t < NH1) {
        float w  = W1[f * NH1 + t];
        float bb = b1[f * NH1 + t];
        w1s[t] = w; b1s[t] = bb;
        tkey[t] = (w != 0.0f) ? (-bb / w) : INFINITY;   // w==0: never toggled
        tidx[t] = t;
    }
    __syncthreads();

    // bitonic sort of 128 (key asc, payload idx); 64 comparators
    for (int size = 2; size <= NH1; size <<= 1) {
        for (int stride = size >> 1; stride > 0; stride >>= 1) {
            if (t < 64) {
                int pos = ((t / stride) * (stride << 1)) + (t % stride);
                int par = pos + stride;
                bool up = ((pos & size) == 0);
                float a = tkey[pos], c = tkey[par];
                int  ia = tidx[pos], ic = tidx[par];
                if ((a > c) == up) {
                    tkey[pos] = c; tkey[par] = a;
                    tidx[pos] = ic; tidx[par] = ia;
                }
            }
            __syncthreads();
        }
    }

    // chunked scan: 512 threads = (k = t&63) x (chunk c = t>>6, 16 j/ranks each)
    {
        const int k = t & 63, c = t >> 6;
        float bw = 0.0f, bbp = 0.0f, dw = 0.0f, db = 0.0f;
        #pragma unroll 4
        for (int i = 0; i < 16; ++i) {
            int j = c * 16 + i;    // rank-0 base: w<0 active; w==0&&b>0 const-on
            float w = w1s[j], bv = b1s[j], w2v = gw2[j * NH2 + k];
            if (w < 0.0f) { bw = fmaf(w, w2v, bw); bbp = fmaf(bv, w2v, bbp); }
            else if (w == 0.0f && bv > 0.0f) { bbp = fmaf(bv, w2v, bbp); }
            int jj = tidx[c * 16 + i];   // toggle-delta partial
            float ww = w1s[jj], bv2 = b1s[jj], w2x = gw2[jj * NH2 + k];
            float s = (ww > 0.0f) ? 1.0f : ((ww < 0.0f) ? -1.0f : 0.0f);
            dw = fmaf(s * ww,  w2x, dw);
            db = fmaf(s * bv2, w2x, db);
        }
        Pbw[c][k] = bw; Pbb[c][k] = bbp; Pdw[c][k] = dw; Pdb[c][k] = db;
    }
    __syncthreads();
    {
        const int k = t & 63, c = t >> 6;
        float accw = 0.0f;
        float accb = b2[f * NH2 + k];    // b2 seed (round-8 lesson)
        #pragma unroll
        for (int c2 = 0; c2 < 8; ++c2) { accw += Pbw[c2][k]; accb += Pbb[c2][k]; }
        for (int c2 = 0; c2 < c; ++c2) { accw += Pdw[c2][k]; accb += Pdb[c2][k]; }
        // layout per row: Sw halves [0..63], Sb halves [64..127], pad to 136
        if (c == 0) {
            SPh[k]      = (_Float16)accw;          // rank-0 row
            SPh[64 + k] = (_Float16)accb;
        }
        #pragma unroll 4
        for (int i = 0; i < 16; ++i) {
            int r = c * 16 + i;
            int j = tidx[r];                       // uniform per chunk -> broadcast
            float w = w1s[j], bv = b1s[j], w2v = gw2[j * NH2 + k];
            float s = (w > 0.0f) ? 1.0f : ((w < 0.0f) ? -1.0f : 0.0f);
            accw = fmaf(s * w,  w2v, accw);
            accb = fmaf(s * bv, w2v, accb);
            SPh[(r + 1) * ROWH + k]      = (_Float16)accw;
            SPh[(r + 1) * ROWH + 64 + k] = (_Float16)accb;
        }
    }
    __syncthreads();

    // coalesced copy-out: tkey[128] then the table flat
    unsigned* __restrict__ wsf = ws + (size_t)f * TBLDW;
    if (t < NH1) wsf[t] = __float_as_uint(tkey[t]);
    const u32x4* src = (const u32x4*)SP4;
    u32x4* dst = (u32x4*)(wsf + NH1);
    #pragma unroll 2
    for (int i = t; i < NRANK * ROW4; i += 512) dst[i] = src[i];
}

// ---------------- main: 512 thr, one block = (feature, batch quarter) ----------------
__global__ __launch_bounds__(512, 8) void nam_main(
    const float* __restrict__ x,      // [B][F], strided reads (L3 absorbs reuse)
    const float* __restrict__ W3, const float* __restrict__ b3,
    const float* __restrict__ W4, const float* __restrict__ b4,
    const unsigned* __restrict__ ws,
    float* __restrict__ out)
{
    __shared__ u32x4 SP4[NRANK * ROW4];    // 35.1 KB packed f16 table
    __shared__ float tkey[NH1];

    const int f  = blockIdx.x >> 2;        // feature
    const int qt = blockIdx.x & 3;         // batch quarter (2048 elems)
    const int t  = (int)threadIdx.x;

    // stage table from ws (L3-served; 9 MB total, read 4x)
    const unsigned* __restrict__ wsf = ws + (size_t)f * TBLDW;
    if (t < NH1) tkey[t] = __uint_as_float(wsf[t]);
    {
        const u32x4* src = (const u32x4*)(wsf + NH1);
        #pragma unroll 2
        for (int i = t; i < NRANK * ROW4; i += 512) SP4[i] = src[i];
    }
    __syncthreads();

    // ======== MFMA main loop, 32x32x16 f16 (A = W3^T, B = h2) ========
    const int lane = t & 63, wv = t >> 6;   // 8 waves
    const int n = lane & 31, q2 = lane >> 5;

    // A-frags: A[m=lane&31][k=(lane>>5)*8+j] = W3[kk][ch=m]; 4 K-tiles of 16
    const float* __restrict__ w3g = W3 + f * NH2 * NH3;
    h16x8 A0, A1, A2, A3;
    #pragma unroll
    for (int j = 0; j < 8; ++j) {
        int kk = q2 * 8 + j;
        A0[j] = (_Float16)w3g[kk * NH3 + n];
        A1[j] = (_Float16)w3g[(kk + 16) * NH3 + n];
        A2[j] = (_Float16)w3g[(kk + 32) * NH3 + n];
        A3[j] = (_Float16)w3g[(kk + 48) * NH3 + n];
    }
    // per-lane channel constants for the 16 C/D rows:
    // row(reg) = (reg&3) + 8*(reg>>2) + 4*q2
    float b3r[16], w4r[16];
    #pragma unroll
    for (int reg = 0; reg < 16; ++reg) {
        int row = (reg & 3) + 8 * (reg >> 2) + 4 * q2;
        b3r[reg] = b3[f * NH3 + row];
        w4r[reg] = W4[f * NH3 + row];
    }
    const float b4f = b4[f];
    // register-tree search levels s=64/32/16 (7 thresholds)
    const float t63 = tkey[63], t31 = tkey[31], t95 = tkey[95];
    const float t15 = tkey[15], t47 = tkey[47], t79 = tkey[79], t111 = tkey[111];

    #pragma unroll 1
    for (int round = 0; round < 8; ++round) {
        const int base = qt * 2048 + (round * 8 + wv) * 32;  // 32-elem batch tile
        const float xv = x[(size_t)(base + n) * NF + f];

        // rank = #(tkey < xv): 3 register levels + 4 LDS levels
        int r = (t63 < xv) ? 64 : 0;
        {
            float l1 = (r & 64) ? t95 : t31;
            if (l1 < xv) r += 32;
            float m0 = (r & 64) ? t79  : t15;
            float m1 = (r & 64) ? t111 : t47;
            float l2 = (r & 32) ? m1 : m0;
            if (l2 < xv) r += 16;
        }
        #pragma unroll
        for (int s = 8; s > 0; s >>= 1)
            if (tkey[r + s - 1] < xv) r += s;

        // gather lane's pair-dwords for its column n, row r:
        // Sw uint4 tiles T*2+q2 (T=0..3), Sb at +8
        const int ro = r * ROW4;
        u32x4 SW0 = SP4[ro + q2],      SW1 = SP4[ro + 2 + q2];
        u32x4 SW2 = SP4[ro + 4 + q2],  SW3 = SP4[ro + 6 + q2];
        u32x4 SB0 = SP4[ro + 8 + q2],  SB1 = SP4[ro + 10 + q2];
        u32x4 SB2 = SP4[ro + 12 + q2], SB3 = SP4[ro + 14 + q2];

        // B-frags: one pk_fma + pk_max per 2 channels
        const h16x2 xh = {(_Float16)xv, (_Float16)xv};
        u32x4 d0, d1, d2, d3;
        d0.x = pkh2(SW0.x, SB0.x, xh); d0.y = pkh2(SW0.y, SB0.y, xh);
        d0.z = pkh2(SW0.z, SB0.z, xh); d0.w = pkh2(SW0.w, SB0.w, xh);
        d1.x = pkh2(SW1.x, SB1.x, xh); d1.y = pkh2(SW1.y, SB1.y, xh);
        d1.z = pkh2(SW1.z, SB1.z, xh); d1.w = pkh2(SW1.w, SB1.w, xh);
        d2.x = pkh2(SW2.x, SB2.x, xh); d2.y = pkh2(SW2.y, SB2.y, xh);
        d2.z = pkh2(SW2.z, SB2.z, xh); d2.w = pkh2(SW2.w, SB2.w, xh);
        d3.x = pkh2(SW3.x, SB3.x, xh); d3.y = pkh2(SW3.y, SB3.y, xh);
        d3.z = pkh2(SW3.z, SB3.z, xh); d3.w = pkh2(SW3.w, SB3.w, xh);
        h16x8 B0 = __builtin_bit_cast(h16x8, d0);
        h16x8 B1 = __builtin_bit_cast(h16x8, d1);
        h16x8 B2 = __builtin_bit_cast(h16x8, d2);
        h16x8 B3 = __builtin_bit_cast(h16x8, d3);

        // layer 3: D[ch][batch], fp32 acc seeded with b3 rows
        f32x16 acc;
        #pragma unroll
        for (int reg = 0; reg < 16; ++reg) acc[reg] = b3r[reg];
        acc = __builtin_amdgcn_mfma_f32_32x32x16_f16(A0, B0, acc, 0, 0, 0);
        acc = __builtin_amdgcn_mfma_f32_32x32x16_f16(A1, B1, acc, 0, 0, 0);
        acc = __builtin_amdgcn_mfma_f32_32x32x16_f16(A2, B2, acc, 0, 0, 0);
        acc = __builtin_amdgcn_mfma_f32_32x32x16_f16(A3, B3, acc, 0, 0, 0);

        // layer 4: reduce lane's own 16 channel rows, 1 shfl over q2, 1 atomic
        float p = 0.0f;
        #pragma unroll
        for (int reg = 0; reg < 16; ++reg)
            p = fmaf(fmaxf(acc[reg], 0.0f), w4r[reg], p);
        p += __shfl_xor(p, 32);
        if (lane < 32) atomicAdd(&out[base + lane], p + b4f);
    }
}

extern "C" void kernel_launch(void* const* d_in, const int* in_sizes, int n_in,
                              void* d_out, int out_size, void* d_ws, size_t ws_size,
                              hipStream_t stream) {
    const float* x    = (const float*)d_in[0];
    const float* W1   = (const float*)d_in[1];
    const float* b1   = (const float*)d_in[2];
    const float* W2   = (const float*)d_in[3];
    const float* b2   = (const float*)d_in[4];
    const float* W3   = (const float*)d_in[5];
    const float* b3   = (const float*)d_in[6];
    const float* W4   = (const float*)d_in[7];
    const float* b4   = (const float*)d_in[8];
    const float* bias = (const float*)d_in[9];
    float* out   = (float*)d_out;
    unsigned* ws = (unsigned*)d_ws;   // needs 256*TBLDW*4 = 9.2 MB (harness gives >=17 MB)

    // build: 1 block/feature; fuses out-init (bias seed for the atomics)
    build_tables<<<NF, 512, 0, stream>>>(W1, b1, W2, b2, bias, out, ws);
    // main: grid 1024 = (feature, batch quarter); 35.6 KB LDS -> 4 blocks/CU
    nam_main<<<NF * 4, 512, 0, stream>>>(x, W3, b3, W4, b4, ws, out);
}

// Round 17
// 120.420 us; speedup vs baseline: 1.9324x; 1.9324x over previous
//
#include <hip/hip_runtime.h>
#include <math.h>

// Neural Additive Model: 256 per-feature MLPs 1->128->64->32->1 (ReLU), summed.
// B=8192, fp32 in/out.
//
// Exact rank-table decomposition: pre-relu h2[b,k] = x_b*Sw[r,k] + Sb[r,k],
// r = #(sorted layer-1 thresholds < x_b). Layer 3 on f16 MFMA 32x32x16
// (A=W3^T, B=h2), layer 4 reduced in-register + 1 shfl, 1 atomic/elem.
//
// Round 17: ONE-LINE fix of R16. __launch_bounds__ second-arg 8 empirically
// makes the allocator target 32 VGPRs and spill the MFMA accumulators
// (R14: (1024,8) -> VGPR 32 + 400 MB spill; R16: (512,8) -> same). Second-arg
// 4 gives 48 VGPRs, no spill (R15). Empirical rule on this toolchain:
// threads_per_block * arg <= 2048. nam_main -> launch_bounds(512, 4):
// VGPR cap >= 64 >= the 48 needed, 4 x 512-thr blocks/CU (LDS 143 KB < 160).
// Everything else identical to R16 (split build/main, table via ws).

#define NF   256
#define NH1  128
#define NH2  64
#define NH3  32
#define NB   8192

#define NRANK 129
#define ROW4  17                      // uint4 per table row (16 data + 1 pad)
#define ROWH  136                     // halfwords per row
#define TBLDW 8960                    // dword stride per feature in ws

typedef float    f32x16 __attribute__((ext_vector_type(16)));
typedef unsigned u32x4  __attribute__((ext_vector_type(4)));
typedef _Float16 h16x2  __attribute__((ext_vector_type(2)));
typedef _Float16 h16x8  __attribute__((ext_vector_type(8)));

// h2 pair: relu(x*Sw + Sb) on 2 packed f16 channels -> one B-frag dword
__device__ __forceinline__ unsigned pkh2(unsigned sw, unsigned sb, h16x2 xh) {
    h16x2 r = __builtin_elementwise_fma(xh, __builtin_bit_cast(h16x2, sw),
                                            __builtin_bit_cast(h16x2, sb));
    h16x2 hz = {(_Float16)0.f, (_Float16)0.f};
    return __builtin_bit_cast(unsigned, __builtin_elementwise_max(r, hz));
}

// ---------------- build: one block (512 thr) per feature; table -> ws ----------------
__global__ __launch_bounds__(512) void build_tables(
    const float* __restrict__ W1, const float* __restrict__ b1,
    const float* __restrict__ W2, const float* __restrict__ b2,
    const float* __restrict__ bias, float* __restrict__ out,
    unsigned* __restrict__ ws)
{
    __shared__ u32x4 SP4[NRANK * ROW4];    // 35.1 KB packed f16 table
    __shared__ float tkey[NH1];
    __shared__ int   tidx[NH1];
    __shared__ float w1s[NH1], b1s[NH1];
    __shared__ float Pbw[8][NH2], Pbb[8][NH2], Pdw[8][NH2], Pdb[8][NH2]; // 8 KB

    const int f = blockIdx.x;
    const int t = (int)threadIdx.x;
    _Float16* SPh = (_Float16*)SP4;

    // fused out-init (out poisoned before every launch; atomics add onto bias)
    const int gid = f * 512 + t;
    if (gid < NB) out[gid] = bias[0];

    const float* __restrict__ gw2 = W2 + (size_t)f * NH1 * NH2;
    if (t < NH1) {
        float w  = W1[f * NH1 + t];
        float bb = b1[f * NH1 + t];
        w1s[t] = w; b1s[t] = bb;
        tkey[t] = (w != 0.0f) ? (-bb / w) : INFINITY;   // w==0: never toggled
        tidx[t] = t;
    }
    __syncthreads();

    // bitonic sort of 128 (key asc, payload idx); 64 comparators
    for (int size = 2; size <= NH1; size <<= 1) {
        for (int stride = size >> 1; stride > 0; stride >>= 1) {
            if (t < 64) {
                int pos = ((t / stride) * (stride << 1)) + (t % stride);
                int par = pos + stride;
                bool up = ((pos & size) == 0);
                float a = tkey[pos], c = tkey[par];
                int  ia = tidx[pos], ic = tidx[par];
                if ((a > c) == up) {
                    tkey[pos] = c; tkey[par] = a;
                    tidx[pos] = ic; tidx[par] = ia;
                }
            }
            __syncthreads();
        }
    }

    // chunked scan: 512 threads = (k = t&63) x (chunk c = t>>6, 16 j/ranks each)
    {
        const int k = t & 63, c = t >> 6;
        float bw = 0.0f, bbp = 0.0f, dw = 0.0f, db = 0.0f;
        #pragma unroll 4
        for (int i = 0; i < 16; ++i) {
            int j = c * 16 + i;    // rank-0 base: w<0 active; w==0&&b>0 const-on
            float w = w1s[j], bv = b1s[j], w2v = gw2[j * NH2 + k];
            if (w < 0.0f) { bw = fmaf(w, w2v, bw); bbp = fmaf(bv, w2v, bbp); }
            else if (w == 0.0f && bv > 0.0f) { bbp = fmaf(bv, w2v, bbp); }
            int jj = tidx[c * 16 + i];   // toggle-delta partial
            float ww = w1s[jj], bv2 = b1s[jj], w2x = gw2[jj * NH2 + k];
            float s = (ww > 0.0f) ? 1.0f : ((ww < 0.0f) ? -1.0f : 0.0f);
            dw = fmaf(s * ww,  w2x, dw);
            db = fmaf(s * bv2, w2x, db);
        }
        Pbw[c][k] = bw; Pbb[c][k] = bbp; Pdw[c][k] = dw; Pdb[c][k] = db;
    }
    __syncthreads();
    {
        const int k = t & 63, c = t >> 6;
        float accw = 0.0f;
        float accb = b2[f * NH2 + k];    // b2 seed (round-8 lesson)
        #pragma unroll
        for (int c2 = 0; c2 < 8; ++c2) { accw += Pbw[c2][k]; accb += Pbb[c2][k]; }
        for (int c2 = 0; c2 < c; ++c2) { accw += Pdw[c2][k]; accb += Pdb[c2][k]; }
        // layout per row: Sw halves [0..63], Sb halves [64..127], pad to 136
        if (c == 0) {
            SPh[k]      = (_Float16)accw;          // rank-0 row
            SPh[64 + k] = (_Float16)accb;
        }
        #pragma unroll 4
        for (int i = 0; i < 16; ++i) {
            int r = c * 16 + i;
            int j = tidx[r];                       // uniform per chunk -> broadcast
            float w = w1s[j], bv = b1s[j], w2v = gw2[j * NH2 + k];
            float s = (w > 0.0f) ? 1.0f : ((w < 0.0f) ? -1.0f : 0.0f);
            accw = fmaf(s * w,  w2v, accw);
            accb = fmaf(s * bv, w2v, accb);
            SPh[(r + 1) * ROWH + k]      = (_Float16)accw;
            SPh[(r + 1) * ROWH + 64 + k] = (_Float16)accb;
        }
    }
    __syncthreads();

    // coalesced copy-out: tkey[128] then the table flat
    unsigned* __restrict__ wsf = ws + (size_t)f * TBLDW;
    if (t < NH1) wsf[t] = __float_as_uint(tkey[t]);
    const u32x4* src = (const u32x4*)SP4;
    u32x4* dst = (u32x4*)(wsf + NH1);
    #pragma unroll 2
    for (int i = t; i < NRANK * ROW4; i += 512) dst[i] = src[i];
}

// ---------------- main: 512 thr, one block = (feature, batch quarter) ----------------
__global__ __launch_bounds__(512, 4) void nam_main(
    const float* __restrict__ x,      // [B][F], strided reads (L3 absorbs reuse)
    const float* __restrict__ W3, const float* __restrict__ b3,
    const float* __restrict__ W4, const float* __restrict__ b4,
    const unsigned* __restrict__ ws,
    float* __restrict__ out)
{
    __shared__ u32x4 SP4[NRANK * ROW4];    // 35.1 KB packed f16 table
    __shared__ float tkey[NH1];

    const int f  = blockIdx.x >> 2;        // feature
    const int qt = blockIdx.x & 3;         // batch quarter (2048 elems)
    const int t  = (int)threadIdx.x;

    // stage table from ws (L3-served; 9 MB total, read 4x)
    const unsigned* __restrict__ wsf = ws + (size_t)f * TBLDW;
    if (t < NH1) tkey[t] = __uint_as_float(wsf[t]);
    {
        const u32x4* src = (const u32x4*)(wsf + NH1);
        #pragma unroll 2
        for (int i = t; i < NRANK * ROW4; i += 512) SP4[i] = src[i];
    }
    __syncthreads();

    // ======== MFMA main loop, 32x32x16 f16 (A = W3^T, B = h2) ========
    const int lane = t & 63, wv = t >> 6;   // 8 waves
    const int n = lane & 31, q2 = lane >> 5;

    // A-frags: A[m=lane&31][k=(lane>>5)*8+j] = W3[kk][ch=m]; 4 K-tiles of 16
    const float* __restrict__ w3g = W3 + f * NH2 * NH3;
    h16x8 A0, A1, A2, A3;
    #pragma unroll
    for (int j = 0; j < 8; ++j) {
        int kk = q2 * 8 + j;
        A0[j] = (_Float16)w3g[kk * NH3 + n];
        A1[j] = (_Float16)w3g[(kk + 16) * NH3 + n];
        A2[j] = (_Float16)w3g[(kk + 32) * NH3 + n];
        A3[j] = (_Float16)w3g[(kk + 48) * NH3 + n];
    }
    // per-lane channel constants for the 16 C/D rows:
    // row(reg) = (reg&3) + 8*(reg>>2) + 4*q2
    float b3r[16], w4r[16];
    #pragma unroll
    for (int reg = 0; reg < 16; ++reg) {
        int row = (reg & 3) + 8 * (reg >> 2) + 4 * q2;
        b3r[reg] = b3[f * NH3 + row];
        w4r[reg] = W4[f * NH3 + row];
    }
    const float b4f = b4[f];
    // register-tree search levels s=64/32/16 (7 thresholds)
    const float t63 = tkey[63], t31 = tkey[31], t95 = tkey[95];
    const float t15 = tkey[15], t47 = tkey[47], t79 = tkey[79], t111 = tkey[111];

    #pragma unroll 1
    for (int round = 0; round < 8; ++round) {
        const int base = qt * 2048 + (round * 8 + wv) * 32;  // 32-elem batch tile
        const float xv = x[(size_t)(base + n) * NF + f];

        // rank = #(tkey < xv): 3 register levels + 4 LDS levels
        int r = (t63 < xv) ? 64 : 0;
        {
            float l1 = (r & 64) ? t95 : t31;
            if (l1 < xv) r += 32;
            float m0 = (r & 64) ? t79  : t15;
            float m1 = (r & 64) ? t111 : t47;
            float l2 = (r & 32) ? m1 : m0;
            if (l2 < xv) r += 16;
        }
        #pragma unroll
        for (int s = 8; s > 0; s >>= 1)
            if (tkey[r + s - 1] < xv) r += s;

        // gather lane's pair-dwords for its column n, row r:
        // Sw uint4 tiles T*2+q2 (T=0..3), Sb at +8
        const int ro = r * ROW4;
        u32x4 SW0 = SP4[ro + q2],      SW1 = SP4[ro + 2 + q2];
        u32x4 SW2 = SP4[ro + 4 + q2],  SW3 = SP4[ro + 6 + q2];
        u32x4 SB0 = SP4[ro + 8 + q2],  SB1 = SP4[ro + 10 + q2];
        u32x4 SB2 = SP4[ro + 12 + q2], SB3 = SP4[ro + 14 + q2];

        // B-frags: one pk_fma + pk_max per 2 channels
        const h16x2 xh = {(_Float16)xv, (_Float16)xv};
        u32x4 d0, d1, d2, d3;
        d0.x = pkh2(SW0.x, SB0.x, xh); d0.y = pkh2(SW0.y, SB0.y, xh);
        d0.z = pkh2(SW0.z, SB0.z, xh); d0.w = pkh2(SW0.w, SB0.w, xh);
        d1.x = pkh2(SW1.x, SB1.x, xh); d1.y = pkh2(SW1.y, SB1.y, xh);
        d1.z = pkh2(SW1.z, SB1.z, xh); d1.w = pkh2(SW1.w, SB1.w, xh);
        d2.x = pkh2(SW2.x, SB2.x, xh); d2.y = pkh2(SW2.y, SB2.y, xh);
        d2.z = pkh2(SW2.z, SB2.z, xh); d2.w = pkh2(SW2.w, SB2.w, xh);
        d3.x = pkh2(SW3.x, SB3.x, xh); d3.y = pkh2(SW3.y, SB3.y, xh);
        d3.z = pkh2(SW3.z, SB3.z, xh); d3.w = pkh2(SW3.w, SB3.w, xh);
        h16x8 B0 = __builtin_bit_cast(h16x8, d0);
        h16x8 B1 = __builtin_bit_cast(h16x8, d1);
        h16x8 B2 = __builtin_bit_cast(h16x8, d2);
        h16x8 B3 = __builtin_bit_cast(h16x8, d3);

        // layer 3: D[ch][batch], fp32 acc seeded with b3 rows
        f32x16 acc;
        #pragma unroll
        for (int reg = 0; reg < 16; ++reg) acc[reg] = b3r[reg];
        acc = __builtin_amdgcn_mfma_f32_32x32x16_f16(A0, B0, acc, 0, 0, 0);
        acc = __builtin_amdgcn_mfma_f32_32x32x16_f16(A1, B1, acc, 0, 0, 0);
        acc = __builtin_amdgcn_mfma_f32_32x32x16_f16(A2, B2, acc, 0, 0, 0);
        acc = __builtin_amdgcn_mfma_f32_32x32x16_f16(A3, B3, acc, 0, 0, 0);

        // layer 4: reduce lane's own 16 channel rows, 1 shfl over q2, 1 atomic
        float p = 0.0f;
        #pragma unroll
        for (int reg = 0; reg < 16; ++reg)
            p = fmaf(fmaxf(acc[reg], 0.0f), w4r[reg], p);
        p += __shfl_xor(p, 32);
        if (lane < 32) atomicAdd(&out[base + lane], p + b4f);
    }
}

extern "C" void kernel_launch(void* const* d_in, const int* in_sizes, int n_in,
                              void* d_out, int out_size, void* d_ws, size_t ws_size,
                              hipStream_t stream) {
    const float* x    = (const float*)d_in[0];
    const float* W1   = (const float*)d_in[1];
    const float* b1   = (const float*)d_in[2];
    const float* W2   = (const float*)d_in[3];
    const float* b2   = (const float*)d_in[4];
    const float* W3   = (const float*)d_in[5];
    const float* b3   = (const float*)d_in[6];
    const float* W4   = (const float*)d_in[7];
    const float* b4   = (const float*)d_in[8];
    const float* bias = (const float*)d_in[9];
    float* out   = (float*)d_out;
    unsigned* ws = (unsigned*)d_ws;   // needs 256*TBLDW*4 = 9.2 MB

    // build: 1 block/feature; fuses out-init (bias seed for the atomics)
    build_tables<<<NF, 512, 0, stream>>>(W1, b1, W2, b2, bias, out, ws);
    // main: grid 1024 = (feature, batch quarter); 35.6 KB LDS -> 4 blocks/CU
    nam_main<<<NF * 4, 512, 0, stream>>>(x, W3, b3, W4, b4, ws, out);
}